// Round 9
// baseline (251.163 us; speedup 1.0000x reference)
//
#include <hip/hip_runtime.h>

// B=16, N=1024, M=8192.
//   d[b,n,m] = || binder[b,n,:] - target[m,:] ||
//   attract[b] = mean of 204 smallest (min_m d) over n;  repel[b] = sum relu(3-d)^2
//   out[b] = 10*attract + 5*repel
//
// R11 (R10 post-mortem: falsifier fired -- halving LDS reads didn't move the
// total (89.1 vs 90.9), so pair is NOT LDS-co-bound; the controllable residue
// is reduce (~8-10us) + dispatch gaps (~7-10us). Fill (41.7us, 256MiB harness
// poison) is fixed):
//  - FUSE reduce into pair via the split-K last-block-done pattern: each block
//    after its streaming stores does threadfence + atomicAdd ticket on
//    counter[b]; the block drawing ticket SL-1 acquires, folds the 128 slice
//    partials for its b (512KB, 256thr, unroll-8 MLP, overlapped with other
//    b's pair blocks), radix-selects, writes out[b]. Reduce dispatch gone.
//  - counters: 64B hipMemsetAsync (capture-safe, proven R3-R5).
//  - hot loop identical to R8 (isolate the structural delta).

#define BB 16
#define NN 1024
#define MM 8192
#define SL 128              // M-slices
#define MSL (MM / SL)       // 64 targets per slice
#define KSEL 204            // int(0.2 * 1024)

__global__ __launch_bounds__(256, 8) void binder_fused_kernel(
    const float* __restrict__ binder,    // [B, N, 3]
    const float* __restrict__ target,    // [M, 3]
    float* __restrict__ min_part,        // [B, SL, N] partial min d^2
    float* __restrict__ repel_part,      // [B, SL]
    unsigned* __restrict__ counters,     // [B] pre-zeroed tickets
    float* __restrict__ out)             // [B]
{
    __shared__ float4 t4[MSL];           // 1KB: (-2tx, -2ty, -2tz, ||t||^2)
    __shared__ float wred[4];
    __shared__ unsigned ticket_s;
    // select-phase LDS (disjoint lifetime, small)
    __shared__ int cnt[256];
    __shared__ int wsum[4];
    __shared__ int bc_bin, bc_rem;
    __shared__ float swred[4];
    __shared__ float swred2[4];

    const int s    = blockIdx.x;
    const int b    = blockIdx.y;
    const int tid  = threadIdx.x;
    const int lane = tid & 63;
    const int wid  = tid >> 6;

    if (tid < MSL) {
        const float* tp = target + (size_t)(s * MSL + tid) * 3;
        const float tx = tp[0], ty = tp[1], tz = tp[2];
        t4[tid] = make_float4(-2.0f * tx, -2.0f * ty, -2.0f * tz,
                              fmaf(tx, tx, fmaf(ty, ty, tz * tz)));
    }
    __syncthreads();

    // 4 binder points per thread; 48B contiguous/lane, 16B-aligned.
    const float* bp = binder + ((size_t)b * NN + tid * 4) * 3;
    const float4 f0 = ((const float4*)bp)[0];
    const float4 f1 = ((const float4*)bp)[1];
    const float4 f2 = ((const float4*)bp)[2];
    const float x0 = f0.x, y0 = f0.y, z0 = f0.z;
    const float x1 = f0.w, y1 = f1.x, z1 = f1.y;
    const float x2 = f1.z, y2 = f1.w, z2 = f2.x;
    const float x3 = f2.y, y3 = f2.z, z3 = f2.w;

    const float bb0 = fmaf(x0, x0, fmaf(y0, y0, z0 * z0));
    const float bb1 = fmaf(x1, x1, fmaf(y1, y1, z1 * z1));
    const float bb2 = fmaf(x2, x2, fmaf(y2, y2, z2 * z2));
    const float bb3 = fmaf(x3, x3, fmaf(y3, y3, z3 * z3));
    const float th0 = 9.0f - bb0, th1 = 9.0f - bb1;
    const float th2 = 9.0f - bb2, th3 = 9.0f - bb3;

    float m0 = 3.4e38f, m1 = 3.4e38f, m2 = 3.4e38f, m3 = 3.4e38f;
    float repel = 0.0f;

#pragma unroll 4
    for (int m = 0; m < MSL; ++m) {
        const float4 t = t4[m];   // wave-uniform addr -> broadcast b128
        const float e0 = fmaf(x0, t.x, fmaf(y0, t.y, fmaf(z0, t.z, t.w)));
        const float e1 = fmaf(x1, t.x, fmaf(y1, t.y, fmaf(z1, t.z, t.w)));
        const float e2 = fmaf(x2, t.x, fmaf(y2, t.y, fmaf(z2, t.z, t.w)));
        const float e3 = fmaf(x3, t.x, fmaf(y3, t.y, fmaf(z3, t.z, t.w)));
        m0 = fminf(m0, e0);
        m1 = fminf(m1, e1);
        m2 = fminf(m2, e2);
        m3 = fminf(m3, e3);
        // per-point clash: e < 9-bb <=> d^2 < 9; non-clash lanes clamp to 0.
        if (__any(e0 < th0)) {
            const float c = fmaxf(3.0f - __builtin_amdgcn_sqrtf(fmaxf(bb0 + e0, 0.0f)), 0.0f);
            repel = fmaf(c, c, repel);
        }
        if (__any(e1 < th1)) {
            const float c = fmaxf(3.0f - __builtin_amdgcn_sqrtf(fmaxf(bb1 + e1, 0.0f)), 0.0f);
            repel = fmaf(c, c, repel);
        }
        if (__any(e2 < th2)) {
            const float c = fmaxf(3.0f - __builtin_amdgcn_sqrtf(fmaxf(bb2 + e2, 0.0f)), 0.0f);
            repel = fmaf(c, c, repel);
        }
        if (__any(e3 < th3)) {
            const float c = fmaxf(3.0f - __builtin_amdgcn_sqrtf(fmaxf(bb3 + e3, 0.0f)), 0.0f);
            repel = fmaf(c, c, repel);
        }
    }

    // plain coalesced store of this slice's partial min d^2 (no atomics)
    float4* op = (float4*)(min_part + ((size_t)b * SL + s) * NN) + tid;
    *op = make_float4(fmaxf(bb0 + m0, 0.0f), fmaxf(bb1 + m1, 0.0f),
                      fmaxf(bb2 + m2, 0.0f), fmaxf(bb3 + m3, 0.0f));

    // repel block-reduce: wave shuffle then 4-slot LDS
#pragma unroll
    for (int off = 32; off > 0; off >>= 1) repel += __shfl_down(repel, off);
    if (lane == 0) wred[wid] = repel;
    __syncthreads();
    if (tid == 0) repel_part[b * SL + s] = wred[0] + wred[1] + wred[2] + wred[3];

    // ---- completion ticket (split-K last-block-done pattern) ----
    __threadfence();                       // release: our stores device-visible
    __syncthreads();                       // all threads' fences done
    if (tid == 0) ticket_s = atomicAdd(&counters[b], 1u);
    __syncthreads();
    if (ticket_s != SL - 1) return;        // not the last block for this b
    __threadfence();                       // acquire: see all blocks' stores

    // ---- fold: 256 threads, thread owns float4 column tid ----
    const float* base = min_part + (size_t)b * SL * NN;
    float mn0 = 3.4e38f, mn1 = 3.4e38f, mn2 = 3.4e38f, mn3 = 3.4e38f;
#pragma unroll 8
    for (int s2 = 0; s2 < SL; ++s2) {
        const float4 v = ((const float4*)(base + (size_t)s2 * NN))[tid];
        mn0 = fminf(mn0, v.x);
        mn1 = fminf(mn1, v.y);
        mn2 = fminf(mn2, v.z);
        mn3 = fminf(mn3, v.w);
    }
    const unsigned uu[4] = {__float_as_uint(mn0), __float_as_uint(mn1),
                            __float_as_uint(mn2), __float_as_uint(mn3)};

    // ---- radix-256 select of the KSEL-th smallest d^2 bits, MSB-first ----
    unsigned prefix = 0u;
    int rem = KSEL;
#pragma unroll
    for (int shift = 24; shift >= 0; shift -= 8) {
        cnt[tid] = 0;
        __syncthreads();
        const unsigned hmask = (shift == 24) ? 0u : (0xFFFFFFFFu << (shift + 8));
#pragma unroll
        for (int p = 0; p < 4; ++p)
            if ((uu[p] & hmask) == (prefix & hmask))
                atomicAdd(&cnt[(uu[p] >> shift) & 255], 1);
        __syncthreads();
        const int orig = cnt[tid];
        int v = orig;
#pragma unroll
        for (int st = 1; st < 64; st <<= 1) {
            const int t = __shfl_up(v, st);
            if (lane >= st) v += t;
        }
        if (lane == 63) wsum[wid] = v;
        __syncthreads();
        int off = 0;
        for (int w = 0; w < wid; ++w) off += wsum[w];
        const int incl = v + off;
        const int excl = incl - orig;
        if (rem > excl && rem <= incl) {   // unique tid (orig>0 there)
            bc_bin = tid;
            bc_rem = rem - excl;
        }
        __syncthreads();
        prefix |= ((unsigned)bc_bin) << shift;
        rem = bc_rem;
        __syncthreads();
    }
    // prefix = T (exact bits of KSEL-th smallest d2); rem = #ties to take.

    float local = 0.0f;
#pragma unroll
    for (int p = 0; p < 4; ++p)
        if (uu[p] < prefix) local += __builtin_amdgcn_sqrtf(__uint_as_float(uu[p]));
#pragma unroll
    for (int off = 32; off > 0; off >>= 1) local += __shfl_down(local, off);
    if (lane == 0) swred[wid] = local;

    float r = (tid < SL) ? repel_part[b * SL + tid] : 0.0f;
#pragma unroll
    for (int off = 32; off > 0; off >>= 1) r += __shfl_down(r, off);
    if (lane == 0) swred2[wid] = r;
    __syncthreads();

    if (tid == 0) {
        const float total = swred[0] + swred[1] + swred[2] + swred[3]
                          + (float)rem * __builtin_amdgcn_sqrtf(__uint_as_float(prefix));
        const float rp = swred2[0] + swred2[1] + swred2[2] + swred2[3];
        out[b] = 10.0f * (total / (float)KSEL) + 5.0f * rp;
    }
}

extern "C" void kernel_launch(void* const* d_in, const int* in_sizes, int n_in,
                              void* d_out, int out_size, void* d_ws, size_t ws_size,
                              hipStream_t stream) {
    const float* binder = (const float*)d_in[0];   // [16,1024,3] fp32
    const float* target = (const float*)d_in[1];   // [8192,3]   fp32
    float* out = (float*)d_out;                    // [16]       fp32

    // workspace: min_part 8MB | repel_part 8KB | counters 64B
    char* ws = (char*)d_ws;
    float* min_part   = (float*)ws;                 ws += (size_t)BB * SL * NN * sizeof(float);
    float* repel_part = (float*)ws;                 ws += (size_t)BB * SL * sizeof(float);
    unsigned* counters = (unsigned*)ws;

    hipMemsetAsync(counters, 0, BB * sizeof(unsigned), stream);
    dim3 g1(SL, BB);   // 128 x 16 = 2048 blocks -> 8 blocks/CU, 8 waves/SIMD
    binder_fused_kernel<<<g1, 256, 0, stream>>>(binder, target, min_part,
                                                repel_part, counters, out);
}

// Round 10
// 111.633 us; speedup vs baseline: 2.2499x; 2.2499x over previous
//
#include <hip/hip_runtime.h>

// B=16, N=1024, M=8192.
//   d[b,n,m] = || binder[b,n,:] - target[m,:] ||
//   attract[b] = mean of 204 smallest (min_m d) over n;  repel[b] = sum relu(3-d)^2
//   out[b] = 10*attract + 5*repel
//
// R12 (R11 post-mortem: fused last-block-done was 215us -- __threadfence in
// every thread of every block = ~8192 buffer_wbl2 L2-writeback sweeps. Fence
// cost, not protocol cost. R8 budget: fill 41.7 fixed + pair + gap + reduce
// ~8.5 + gaps; reduce+gap is pure overhead):
//  - fence-FREE fused protocol: writers store partials WRITE-THROUGH
//    (__hip_atomic_store SYSTEM relaxed -> global_store sc0 sc1, no dirty L2,
//    no wbl2 ever), s_waitcnt vmcnt(0) + one system-scope ticket fetch_add
//    per block (2048 total).
//  - 16 reader blocks at the grid TAIL (dispatched last, hold <=16/2048 slots;
//    spin with s_sleep on system-scope counter loads). Reader folds its b's
//    512KB via system-scope loads (bypass stale clean L2 lines), radix-selects,
//    writes out[b] -- overlapped with later b's writers.
//  - memset only counters (64B). Hot loop and all arithmetic orders identical
//    to R8 -> bit-identical output.

#define BB 16
#define NN 1024
#define MM 8192
#define SL 128              // M-slices
#define MSL (MM / SL)       // 64 targets per slice
#define KSEL 204            // int(0.2 * 1024)
#define WRITERS (SL * BB)   // 2048 writer blocks

__device__ __forceinline__ unsigned long long pack2(float a, float b) {
    return (unsigned long long)__float_as_uint(a)
         | ((unsigned long long)__float_as_uint(b) << 32);
}

__global__ __launch_bounds__(256, 8) void binder_fused_kernel(
    const float* __restrict__ binder,          // [B, N, 3]
    const float* __restrict__ target,          // [M, 3]
    unsigned long long* __restrict__ min_part, // [B, SL, N/2] packed d^2 pairs
    float* __restrict__ repel_part,            // [B, SL]
    unsigned* __restrict__ counters,           // [B] pre-zeroed tickets
    float* __restrict__ out)                   // [B]
{
    __shared__ float4 t4[MSL];
    __shared__ float wred[4];
    __shared__ int cnt[256];
    __shared__ int wsum[4];
    __shared__ int bc_bin, bc_rem;
    __shared__ float swred[4];
    __shared__ float swred2[4];

    const int bid  = blockIdx.x;
    const int tid  = threadIdx.x;
    const int lane = tid & 63;
    const int wid  = tid >> 6;

    if (bid < WRITERS) {
        // ---------------- writer: R8 hot loop, verbatim ----------------
        const int s = bid & (SL - 1);
        const int b = bid >> 7;               // SL == 128

        if (tid < MSL) {
            const float* tp = target + (size_t)(s * MSL + tid) * 3;
            const float tx = tp[0], ty = tp[1], tz = tp[2];
            t4[tid] = make_float4(-2.0f * tx, -2.0f * ty, -2.0f * tz,
                                  fmaf(tx, tx, fmaf(ty, ty, tz * tz)));
        }
        __syncthreads();

        const float* bp = binder + ((size_t)b * NN + tid * 4) * 3;
        const float4 f0 = ((const float4*)bp)[0];
        const float4 f1 = ((const float4*)bp)[1];
        const float4 f2 = ((const float4*)bp)[2];
        const float x0 = f0.x, y0 = f0.y, z0 = f0.z;
        const float x1 = f0.w, y1 = f1.x, z1 = f1.y;
        const float x2 = f1.z, y2 = f1.w, z2 = f2.x;
        const float x3 = f2.y, y3 = f2.z, z3 = f2.w;

        const float bb0 = fmaf(x0, x0, fmaf(y0, y0, z0 * z0));
        const float bb1 = fmaf(x1, x1, fmaf(y1, y1, z1 * z1));
        const float bb2 = fmaf(x2, x2, fmaf(y2, y2, z2 * z2));
        const float bb3 = fmaf(x3, x3, fmaf(y3, y3, z3 * z3));
        const float th0 = 9.0f - bb0, th1 = 9.0f - bb1;
        const float th2 = 9.0f - bb2, th3 = 9.0f - bb3;

        float m0 = 3.4e38f, m1 = 3.4e38f, m2 = 3.4e38f, m3 = 3.4e38f;
        float repel = 0.0f;

#pragma unroll 4
        for (int m = 0; m < MSL; ++m) {
            const float4 t = t4[m];   // wave-uniform addr -> broadcast b128
            const float e0 = fmaf(x0, t.x, fmaf(y0, t.y, fmaf(z0, t.z, t.w)));
            const float e1 = fmaf(x1, t.x, fmaf(y1, t.y, fmaf(z1, t.z, t.w)));
            const float e2 = fmaf(x2, t.x, fmaf(y2, t.y, fmaf(z2, t.z, t.w)));
            const float e3 = fmaf(x3, t.x, fmaf(y3, t.y, fmaf(z3, t.z, t.w)));
            m0 = fminf(m0, e0);
            m1 = fminf(m1, e1);
            m2 = fminf(m2, e2);
            m3 = fminf(m3, e3);
            if (__any(e0 < th0)) {
                const float c = fmaxf(3.0f - __builtin_amdgcn_sqrtf(fmaxf(bb0 + e0, 0.0f)), 0.0f);
                repel = fmaf(c, c, repel);
            }
            if (__any(e1 < th1)) {
                const float c = fmaxf(3.0f - __builtin_amdgcn_sqrtf(fmaxf(bb1 + e1, 0.0f)), 0.0f);
                repel = fmaf(c, c, repel);
            }
            if (__any(e2 < th2)) {
                const float c = fmaxf(3.0f - __builtin_amdgcn_sqrtf(fmaxf(bb2 + e2, 0.0f)), 0.0f);
                repel = fmaf(c, c, repel);
            }
            if (__any(e3 < th3)) {
                const float c = fmaxf(3.0f - __builtin_amdgcn_sqrtf(fmaxf(bb3 + e3, 0.0f)), 0.0f);
                repel = fmaf(c, c, repel);
            }
        }

        // write-through partial stores (sc0 sc1): no dirty L2, reader-visible
        unsigned long long* mp =
            min_part + ((size_t)(b * SL + s) * NN) / 2 + tid * 2;
        const float d0 = fmaxf(bb0 + m0, 0.0f), d1 = fmaxf(bb1 + m1, 0.0f);
        const float d2 = fmaxf(bb2 + m2, 0.0f), d3 = fmaxf(bb3 + m3, 0.0f);
        __hip_atomic_store(&mp[0], pack2(d0, d1), __ATOMIC_RELAXED, __HIP_MEMORY_SCOPE_SYSTEM);
        __hip_atomic_store(&mp[1], pack2(d2, d3), __ATOMIC_RELAXED, __HIP_MEMORY_SCOPE_SYSTEM);

        // repel block-reduce (same tree as R8)
#pragma unroll
        for (int off = 32; off > 0; off >>= 1) repel += __shfl_down(repel, off);
        if (lane == 0) wred[wid] = repel;
        __syncthreads();
        if (tid == 0) {
            const float rsum = wred[0] + wred[1] + wred[2] + wred[3];
            __hip_atomic_store(&repel_part[b * SL + s], rsum,
                               __ATOMIC_RELAXED, __HIP_MEMORY_SCOPE_SYSTEM);
        }

        // completion ticket: drain this wave's stores, then one RMW per block
        asm volatile("s_waitcnt vmcnt(0)" ::: "memory");
        __syncthreads();
        if (tid == 0)
            __hip_atomic_fetch_add(&counters[b], 1u,
                                   __ATOMIC_RELAXED, __HIP_MEMORY_SCOPE_SYSTEM);
        return;
    }

    // ---------------- reader: one block per b, dispatched last ----------------
    const int b = bid - WRITERS;

    if (tid == 0) {
        while (__hip_atomic_load(&counters[b], __ATOMIC_RELAXED,
                                 __HIP_MEMORY_SCOPE_SYSTEM) < SL)
            __builtin_amdgcn_s_sleep(8);
    }
    __syncthreads();

    // fold 128 slice rows (system-scope loads bypass stale clean L2 lines)
    const unsigned long long* base = min_part + (size_t)b * SL * (NN / 2);
    float mn0 = 3.4e38f, mn1 = 3.4e38f, mn2 = 3.4e38f, mn3 = 3.4e38f;
#pragma unroll 8
    for (int s2 = 0; s2 < SL; ++s2) {
        const unsigned long long* mp = base + (size_t)s2 * (NN / 2) + tid * 2;
        const unsigned long long v0 =
            __hip_atomic_load(&mp[0], __ATOMIC_RELAXED, __HIP_MEMORY_SCOPE_SYSTEM);
        const unsigned long long v1 =
            __hip_atomic_load(&mp[1], __ATOMIC_RELAXED, __HIP_MEMORY_SCOPE_SYSTEM);
        mn0 = fminf(mn0, __uint_as_float((unsigned)v0));
        mn1 = fminf(mn1, __uint_as_float((unsigned)(v0 >> 32)));
        mn2 = fminf(mn2, __uint_as_float((unsigned)v1));
        mn3 = fminf(mn3, __uint_as_float((unsigned)(v1 >> 32)));
    }
    const unsigned uu[4] = {__float_as_uint(mn0), __float_as_uint(mn1),
                            __float_as_uint(mn2), __float_as_uint(mn3)};

    // radix-256 select of the KSEL-th smallest d^2 bits, MSB-first
    unsigned prefix = 0u;
    int rem = KSEL;
#pragma unroll
    for (int shift = 24; shift >= 0; shift -= 8) {
        cnt[tid] = 0;
        __syncthreads();
        const unsigned hmask = (shift == 24) ? 0u : (0xFFFFFFFFu << (shift + 8));
#pragma unroll
        for (int p = 0; p < 4; ++p)
            if ((uu[p] & hmask) == (prefix & hmask))
                atomicAdd(&cnt[(uu[p] >> shift) & 255], 1);
        __syncthreads();
        const int orig = cnt[tid];
        int v = orig;
#pragma unroll
        for (int st = 1; st < 64; st <<= 1) {
            const int t = __shfl_up(v, st);
            if (lane >= st) v += t;
        }
        if (lane == 63) wsum[wid] = v;
        __syncthreads();
        int off = 0;
        for (int w = 0; w < wid; ++w) off += wsum[w];
        const int incl = v + off;
        const int excl = incl - orig;
        if (rem > excl && rem <= incl) {   // unique tid (orig>0 there)
            bc_bin = tid;
            bc_rem = rem - excl;
        }
        __syncthreads();
        prefix |= ((unsigned)bc_bin) << shift;
        rem = bc_rem;
        __syncthreads();
    }
    // prefix = T (exact bits of KSEL-th smallest d2); rem = #ties to take.

    float local = 0.0f;
#pragma unroll
    for (int p = 0; p < 4; ++p)
        if (uu[p] < prefix) local += __builtin_amdgcn_sqrtf(__uint_as_float(uu[p]));
#pragma unroll
    for (int off = 32; off > 0; off >>= 1) local += __shfl_down(local, off);
    if (lane == 0) swred[wid] = local;

    float r = 0.0f;
    if (tid < SL)
        r = __hip_atomic_load(&repel_part[b * SL + tid],
                              __ATOMIC_RELAXED, __HIP_MEMORY_SCOPE_SYSTEM);
#pragma unroll
    for (int off = 32; off > 0; off >>= 1) r += __shfl_down(r, off);
    if (lane == 0) swred2[wid] = r;
    __syncthreads();

    if (tid == 0) {
        const float total = swred[0] + swred[1] + swred[2] + swred[3]
                          + (float)rem * __builtin_amdgcn_sqrtf(__uint_as_float(prefix));
        const float rp = swred2[0] + swred2[1] + swred2[2] + swred2[3];
        out[b] = 10.0f * (total / (float)KSEL) + 5.0f * rp;
    }
}

extern "C" void kernel_launch(void* const* d_in, const int* in_sizes, int n_in,
                              void* d_out, int out_size, void* d_ws, size_t ws_size,
                              hipStream_t stream) {
    const float* binder = (const float*)d_in[0];   // [16,1024,3] fp32
    const float* target = (const float*)d_in[1];   // [8192,3]   fp32
    float* out = (float*)d_out;                    // [16]       fp32

    // workspace: min_part 8MB | repel_part 8KB | counters 64B
    char* ws = (char*)d_ws;
    unsigned long long* min_part = (unsigned long long*)ws;
    ws += (size_t)BB * SL * NN * sizeof(float);
    float* repel_part = (float*)ws;
    ws += (size_t)BB * SL * sizeof(float);
    unsigned* counters = (unsigned*)ws;

    hipMemsetAsync(counters, 0, BB * sizeof(unsigned), stream);
    binder_fused_kernel<<<WRITERS + BB, 256, 0, stream>>>(
        binder, target, min_part, repel_part, counters, out);
}

// Round 12
// 103.182 us; speedup vs baseline: 2.4342x; 1.0819x over previous
//
#include <hip/hip_runtime.h>

// B=16, N=1024, M=8192.
//   d[b,n,m] = || binder[b,n,:] - target[m,:] ||
//   attract[b] = mean of 204 smallest (min_m d) over n;  repel[b] = sum relu(3-d)^2
//   out[b] = 10*attract + 5*repel
//
// R13 (R12 post-mortem: BOTH fusion falsifiers fired -- intra-dispatch
// cross-block handoff always pays coherence costs (wbl2 fences: 215us;
// write-through store drains: 63us) exceeding the ~12us dispatch+gap saved.
// End-of-dispatch flush is this chip's cheapest fence. PERMANENT revert to
// R8's 2-dispatch structure):
//  - cycle model of R8 pair loop closes at 126 cyc/iter vs ~60 VALU inventory:
//    ~16cy x 4 `if(__any)` branch bubbles + BB-fragmented scheduling.
//  - this round: BRANCHLESS clash. c = fmax(3-sqrt(fmax(bb+e,0)),0);
//    repel = fma(c,c,repel) unconditionally. Non-clash pairs add exact +0
//    -> repel bit-identical to R8. Straight-line body, unroll 8, compiler
//    can hoist all ds_reads and pipeline fma chains. ~104 cyc/iter predicted.
//  - everything else byte-identical to R8 (best: 89.1us).
// (R11 submission never benched -- GPU broker timeout; resubmitting as-is.)

#define BB 16
#define NN 1024
#define MM 8192
#define SL 128              // M-slices
#define MSL (MM / SL)       // 64 targets per slice
#define KSEL 204            // int(0.2 * 1024)

__global__ __launch_bounds__(256, 8) void binder_pair_kernel(
    const float* __restrict__ binder,    // [B, N, 3]
    const float* __restrict__ target,    // [M, 3]
    float* __restrict__ min_part,        // [B, SL, N] partial min d^2
    float* __restrict__ repel_part)      // [B, SL]
{
    __shared__ float4 t4[MSL];           // 1KB: (-2tx, -2ty, -2tz, ||t||^2)
    __shared__ float wred[4];

    const int s   = blockIdx.x;
    const int b   = blockIdx.y;
    const int tid = threadIdx.x;

    if (tid < MSL) {
        const float* tp = target + (size_t)(s * MSL + tid) * 3;
        const float tx = tp[0], ty = tp[1], tz = tp[2];
        t4[tid] = make_float4(-2.0f * tx, -2.0f * ty, -2.0f * tz,
                              fmaf(tx, tx, fmaf(ty, ty, tz * tz)));
    }
    __syncthreads();

    // 4 binder points per thread; 48B contiguous/lane, 16B-aligned.
    const float* bp = binder + ((size_t)b * NN + tid * 4) * 3;
    const float4 f0 = ((const float4*)bp)[0];
    const float4 f1 = ((const float4*)bp)[1];
    const float4 f2 = ((const float4*)bp)[2];
    const float x0 = f0.x, y0 = f0.y, z0 = f0.z;
    const float x1 = f0.w, y1 = f1.x, z1 = f1.y;
    const float x2 = f1.z, y2 = f1.w, z2 = f2.x;
    const float x3 = f2.y, y3 = f2.z, z3 = f2.w;

    const float bb0 = fmaf(x0, x0, fmaf(y0, y0, z0 * z0));
    const float bb1 = fmaf(x1, x1, fmaf(y1, y1, z1 * z1));
    const float bb2 = fmaf(x2, x2, fmaf(y2, y2, z2 * z2));
    const float bb3 = fmaf(x3, x3, fmaf(y3, y3, z3 * z3));

    float m0 = 3.4e38f, m1 = 3.4e38f, m2 = 3.4e38f, m3 = 3.4e38f;
    float repel = 0.0f;

#pragma unroll 8
    for (int m = 0; m < MSL; ++m) {
        const float4 t = t4[m];   // wave-uniform addr -> broadcast b128
        const float e0 = fmaf(x0, t.x, fmaf(y0, t.y, fmaf(z0, t.z, t.w)));
        const float e1 = fmaf(x1, t.x, fmaf(y1, t.y, fmaf(z1, t.z, t.w)));
        const float e2 = fmaf(x2, t.x, fmaf(y2, t.y, fmaf(z2, t.z, t.w)));
        const float e3 = fmaf(x3, t.x, fmaf(y3, t.y, fmaf(z3, t.z, t.w)));
        m0 = fminf(m0, e0);
        m1 = fminf(m1, e1);
        m2 = fminf(m2, e2);
        m3 = fminf(m3, e3);
        // branchless clash: non-clash pairs give c==0 exactly (d^2>=9 ->
        // 3-sqrt<=0 -> clamped), so repel is bit-identical to the branchy
        // version; straight-line body removes ~16cy/branch bubbles.
        const float c0 = fmaxf(3.0f - __builtin_amdgcn_sqrtf(fmaxf(bb0 + e0, 0.0f)), 0.0f);
        const float c1 = fmaxf(3.0f - __builtin_amdgcn_sqrtf(fmaxf(bb1 + e1, 0.0f)), 0.0f);
        const float c2 = fmaxf(3.0f - __builtin_amdgcn_sqrtf(fmaxf(bb2 + e2, 0.0f)), 0.0f);
        const float c3 = fmaxf(3.0f - __builtin_amdgcn_sqrtf(fmaxf(bb3 + e3, 0.0f)), 0.0f);
        repel = fmaf(c0, c0, repel);
        repel = fmaf(c1, c1, repel);
        repel = fmaf(c2, c2, repel);
        repel = fmaf(c3, c3, repel);
    }

    // plain coalesced store of this slice's partial min d^2 (no atomics)
    float4* op = (float4*)(min_part + ((size_t)b * SL + s) * NN) + tid;
    *op = make_float4(fmaxf(bb0 + m0, 0.0f), fmaxf(bb1 + m1, 0.0f),
                      fmaxf(bb2 + m2, 0.0f), fmaxf(bb3 + m3, 0.0f));

    // repel block-reduce: wave shuffle then 4-slot LDS
#pragma unroll
    for (int off = 32; off > 0; off >>= 1) repel += __shfl_down(repel, off);
    if ((tid & 63) == 0) wred[tid >> 6] = repel;
    __syncthreads();
    if (tid == 0) repel_part[b * SL + s] = wred[0] + wred[1] + wred[2] + wred[3];
}

__global__ __launch_bounds__(256) void binder_reduce_kernel(
    const float* __restrict__ min_part,    // [B, SL, N]
    const float* __restrict__ repel_part,  // [B, SL]
    float* __restrict__ out)               // [B]
{
    __shared__ int cnt[256];
    __shared__ int wsum[4];
    __shared__ int bc_bin, bc_rem;
    __shared__ float wred[4];
    __shared__ float wred2[4];

    const int b    = blockIdx.x;
    const int tid  = threadIdx.x;
    const int lane = tid & 63;
    const int wid  = tid >> 6;

    // fold the SL slice partials during load (each iter = one coalesced 4KB row)
    const float* base = min_part + (size_t)b * SL * NN;
    float mn0 = 3.4e38f, mn1 = 3.4e38f, mn2 = 3.4e38f, mn3 = 3.4e38f;
#pragma unroll 8
    for (int s = 0; s < SL; ++s) {
        const float4 v = ((const float4*)(base + (size_t)s * NN))[tid];
        mn0 = fminf(mn0, v.x);
        mn1 = fminf(mn1, v.y);
        mn2 = fminf(mn2, v.z);
        mn3 = fminf(mn3, v.w);
    }
    const unsigned uu[4] = {__float_as_uint(mn0), __float_as_uint(mn1),
                            __float_as_uint(mn2), __float_as_uint(mn3)};

    // radix-256 select of the KSEL-th smallest d^2 bit pattern, MSB-first.
    // scan per round: intra-wave __shfl_up inclusive scan (no barriers) +
    // 4-entry wave-sum combine -> 4 barriers/round.
    unsigned prefix = 0u;
    int rem = KSEL;
#pragma unroll
    for (int shift = 24; shift >= 0; shift -= 8) {
        cnt[tid] = 0;
        __syncthreads();
        const unsigned hmask = (shift == 24) ? 0u : (0xFFFFFFFFu << (shift + 8));
#pragma unroll
        for (int p = 0; p < 4; ++p)
            if ((uu[p] & hmask) == (prefix & hmask))
                atomicAdd(&cnt[(uu[p] >> shift) & 255], 1);
        __syncthreads();
        const int orig = cnt[tid];
        int v = orig;
#pragma unroll
        for (int s = 1; s < 64; s <<= 1) {
            const int t = __shfl_up(v, s);
            if (lane >= s) v += t;
        }
        if (lane == 63) wsum[wid] = v;
        __syncthreads();
        int off = 0;
        for (int w = 0; w < wid; ++w) off += wsum[w];
        const int incl = v + off;
        const int excl = incl - orig;
        if (rem > excl && rem <= incl) {   // unique tid (orig>0 there)
            bc_bin = tid;
            bc_rem = rem - excl;
        }
        __syncthreads();
        prefix |= ((unsigned)bc_bin) << shift;
        rem = bc_rem;
        __syncthreads();
    }
    // prefix = T (exact bits of KSEL-th smallest d2); rem = #ties to take.

    float local = 0.0f;
#pragma unroll
    for (int p = 0; p < 4; ++p)
        if (uu[p] < prefix) local += __builtin_amdgcn_sqrtf(__uint_as_float(uu[p]));
#pragma unroll
    for (int off = 32; off > 0; off >>= 1) local += __shfl_down(local, off);
    if ((tid & 63) == 0) wred[tid >> 6] = local;

    float r = (tid < SL) ? repel_part[b * SL + tid] : 0.0f;
#pragma unroll
    for (int off = 32; off > 0; off >>= 1) r += __shfl_down(r, off);
    if ((tid & 63) == 0) wred2[tid >> 6] = r;
    __syncthreads();

    if (tid == 0) {
        const float total = wred[0] + wred[1] + wred[2] + wred[3]
                          + (float)rem * __builtin_amdgcn_sqrtf(__uint_as_float(prefix));
        const float rp = wred2[0] + wred2[1] + wred2[2] + wred2[3];
        out[b] = 10.0f * (total / (float)KSEL) + 5.0f * rp;
    }
}

extern "C" void kernel_launch(void* const* d_in, const int* in_sizes, int n_in,
                              void* d_out, int out_size, void* d_ws, size_t ws_size,
                              hipStream_t stream) {
    const float* binder = (const float*)d_in[0];   // [16,1024,3] fp32
    const float* target = (const float*)d_in[1];   // [8192,3]   fp32
    float* out = (float*)d_out;                    // [16]       fp32

    // workspace: min_part 8MB + repel_part 8KB
    float* min_part   = (float*)d_ws;
    float* repel_part = (float*)((char*)d_ws + (size_t)BB * SL * NN * sizeof(float));

    dim3 g1(SL, BB);   // 128 x 16 = 2048 blocks -> 8 blocks/CU, 8 waves/SIMD
    binder_pair_kernel<<<g1, 256, 0, stream>>>(binder, target, min_part, repel_part);
    binder_reduce_kernel<<<BB, 256, 0, stream>>>(min_part, repel_part, out);
}